// Round 14
// baseline (779.784 us; speedup 1.0000x reference)
//
#include <hip/hip_runtime.h>

typedef __bf16 bf16x8 __attribute__((ext_vector_type(8)));
typedef float f32x4 __attribute__((ext_vector_type(4)));
typedef unsigned short u16x8 __attribute__((ext_vector_type(8)));

#define B_SZ 2
#define T_SEQ 2048
#define D_MODEL 2048
#define N_HEADS 16
#define D_HEAD 128
#define D_FF 8192
#define BT (B_SZ * T_SEQ)
#define NT (T_SEQ / 64)

__device__ __forceinline__ unsigned short f2bf(float f) {
  unsigned int u = __builtin_bit_cast(unsigned int, f);
  u += 0x7FFFu + ((u >> 16) & 1u);
  return (unsigned short)(u >> 16);
}
__device__ __forceinline__ float bf2f(unsigned short h) {
  unsigned int u = ((unsigned int)h) << 16;
  return __builtin_bit_cast(float, u);
}

__device__ __forceinline__ void load_lds16(const void* g, void* l) {
  __builtin_amdgcn_global_load_lds(
      (const __attribute__((address_space(1))) unsigned int*)g,
      (__attribute__((address_space(3))) unsigned int*)l, 16, 0, 0);
}

template <int N>
__device__ __forceinline__ void vm_gate() {
  if constexpr (N <= 0)
    asm volatile("s_waitcnt vmcnt(0)" ::: "memory");
  else if constexpr (N == 2)
    asm volatile("s_waitcnt vmcnt(2)" ::: "memory");
  else if constexpr (N == 3)
    asm volatile("s_waitcnt vmcnt(3)" ::: "memory");
  else if constexpr (N == 4)
    asm volatile("s_waitcnt vmcnt(4)" ::: "memory");
  else if constexpr (N == 5)
    asm volatile("s_waitcnt vmcnt(5)" ::: "memory");
  else if constexpr (N == 6)
    asm volatile("s_waitcnt vmcnt(6)" ::: "memory");
  else if constexpr (N == 10)
    asm volatile("s_waitcnt vmcnt(10)" ::: "memory");
  else
    asm volatile("s_waitcnt vmcnt(8)" ::: "memory");
}

// ---------------- transpose + cast: in fp32 [R][C] -> out bf16 [C][R] -------
__global__ __launch_bounds__(256) void transpose_cast_kernel(
    const float* __restrict__ in, unsigned short* __restrict__ out, int R, int C) {
  __shared__ float tile[64][65];
  const int tx = threadIdx.x, ty = threadIdx.y;  // [0,16)
  const int c0 = blockIdx.x * 64, r0 = blockIdx.y * 64;
#pragma unroll
  for (int i = 0; i < 4; ++i) {
    const float4 v = *(const float4*)(in + (long)(r0 + ty + 16 * i) * C + c0 + tx * 4);
    float* tr = &tile[ty + 16 * i][tx * 4];
    tr[0] = v.x; tr[1] = v.y; tr[2] = v.z; tr[3] = v.w;
  }
  __syncthreads();
#pragma unroll
  for (int i = 0; i < 4; ++i) {
    const int cc = ty + 16 * i;
    ushort4 o;
    o.x = f2bf(tile[tx * 4 + 0][cc]);
    o.y = f2bf(tile[tx * 4 + 1][cc]);
    o.z = f2bf(tile[tx * 4 + 2][cc]);
    o.w = f2bf(tile[tx * 4 + 3][cc]);
    *(ushort4*)(out + (long)(c0 + cc) * R + r0 + tx * 4) = o;
  }
}

// ---------------- RMSNorm fp32 row -> bf16 ----------------------------------
__global__ __launch_bounds__(256) void rmsnorm_cast_kernel(
    const float* __restrict__ x, const float* __restrict__ gw,
    unsigned short* __restrict__ out) {
  const int row = blockIdx.x;
  const int tid = threadIdx.x;
  const float* xr = x + (long)row * D_MODEL;
  float4 a = *(const float4*)(xr + tid * 8);
  float4 b = *(const float4*)(xr + tid * 8 + 4);
  float ss = a.x * a.x + a.y * a.y + a.z * a.z + a.w * a.w +
             b.x * b.x + b.y * b.y + b.z * b.z + b.w * b.w;
#pragma unroll
  for (int d = 1; d < 64; d <<= 1) ss += __shfl_xor(ss, d);
  __shared__ float part[4];
  if ((tid & 63) == 0) part[tid >> 6] = ss;
  __syncthreads();
  ss = part[0] + part[1] + part[2] + part[3];
  const float rs = rsqrtf(ss * (1.0f / D_MODEL) + 1e-6f);
  float4 g0 = *(const float4*)(gw + tid * 8);
  float4 g1 = *(const float4*)(gw + tid * 8 + 4);
  ushort4 o0, o1;
  o0.x = f2bf(a.x * rs * g0.x); o0.y = f2bf(a.y * rs * g0.y);
  o0.z = f2bf(a.z * rs * g0.z); o0.w = f2bf(a.w * rs * g0.w);
  o1.x = f2bf(b.x * rs * g1.x); o1.y = f2bf(b.y * rs * g1.y);
  o1.z = f2bf(b.z * rs * g1.z); o1.w = f2bf(b.w * rs * g1.w);
  unsigned short* op = out + (long)row * D_MODEL + tid * 8;
  *(ushort4*)op = o0;
  *(ushort4*)(op + 4) = o1;
}

// ---------------- k-slice-ring pipelined GEMM (champion schedule) -----------
template <int EPI, int WM, int WN, int FM, int FN, bool DUALA = false>
__global__ __launch_bounds__(WM * WN * 64, 2) void gemm_ks_kernel(
    const unsigned short* __restrict__ A, const unsigned short* __restrict__ Bt,
    void* __restrict__ Cout, const void* __restrict__ aux,
    const unsigned short* __restrict__ A2,
    int M, int N, int K, int lda, int ldb, int ldc, int cm, int cn) {
  constexpr int THREADS = WM * WN * 64;
  constexpr int BM = WM * FM * 16;
  constexpr int BN = WN * FN * 16;
  constexpr int ASLOT = BM * 32;
  constexpr int BSLOT = BN * 32;
  constexpr int RPR = THREADS / 4;
  constexpr int LPS = BM / RPR + BN / RPR;  // loads per slice per thread
  __shared__ unsigned short As[4 * ASLOT];
  __shared__ unsigned short Bs[4 * BSLOT];

  const int tid = threadIdx.x;
  const int lane = tid & 63, g = lane >> 4, c = lane & 15;
  const int w = tid >> 6, wr = w / WN, wc = w % WN;

  const int nbn = N / BN;
  const int bid = (int)blockIdx.x;
  const int xcd = bid & 7, idx = bid >> 3;
  const int chn = nbn / cn;
  const int crow = xcd / chn, ccol = xcd % chn;
  const int mr = idx / cn, nc2 = idx % cn;
  const int m0 = (crow * cm + mr) * BM;
  const int n0 = (ccol * cn + nc2) * BN;

  const int nks = K >> 5;
  const int srow = tid >> 2;
  const int kq8 = (tid & 3) * 8;
  const unsigned short* A_ = A + (long)m0 * lda;
  const unsigned short* A2_ = DUALA ? (A2 + (long)m0 * lda) : nullptr;
  const unsigned short* B_ = Bt + (long)n0 * ldb;

  auto stage = [&](int s) {
    const int slot = s & 3;
    const long k32 = (long)s * 32;
    const unsigned short* Ab;
    long akofs;
    if constexpr (DUALA) {
      const int khalf = K >> 1;
      const bool lo = k32 < khalf;
      Ab = lo ? A_ : A2_;
      akofs = (lo ? k32 : k32 - khalf) + kq8;
    } else {
      Ab = A_;
      akofs = k32 + kq8;
    }
    const long bkofs = k32 + kq8;
#pragma unroll
    for (int j = 0; j < BM / RPR; ++j)
      load_lds16(Ab + (long)(j * RPR + srow) * lda + akofs,
                 &As[slot * ASLOT + (j * THREADS + tid) * 8]);
#pragma unroll
    for (int j = 0; j < BN / RPR; ++j)
      load_lds16(B_ + (long)(j * RPR + srow) * ldb + bkofs,
                 &Bs[slot * BSLOT + (j * THREADS + tid) * 8]);
  };

  f32x4 acc[FM][FN] = {};

  stage(0);
  if (nks > 1) stage(1);
  if (nks > 2) stage(2);
  vm_gate<2 * LPS>();
  __builtin_amdgcn_sched_barrier(0);
  __builtin_amdgcn_s_barrier();

  for (int s = 0; s < nks; ++s) {
    const int slot = s & 3;
    const unsigned short* Ap = &As[slot * ASLOT] + (wr * FM * 16 + c) * 32 + g * 8;
    const unsigned short* Bp = &Bs[slot * BSLOT] + (wc * FN * 16 + c) * 32 + g * 8;
    bf16x8 fa[FM], fb[FN];
#pragma unroll
    for (int fm = 0; fm < FM; ++fm) fa[fm] = *(const bf16x8*)(Ap + fm * 512);
#pragma unroll
    for (int fn = 0; fn < FN; ++fn) fb[fn] = *(const bf16x8*)(Bp + fn * 512);
    if (s + 3 < nks) stage(s + 3);
    __builtin_amdgcn_s_setprio(1);
#pragma unroll
    for (int fm = 0; fm < FM; ++fm)
#pragma unroll
      for (int fn = 0; fn < FN; ++fn)
        acc[fm][fn] = __builtin_amdgcn_mfma_f32_16x16x32_bf16(fa[fm], fb[fn], acc[fm][fn], 0, 0, 0);
    __builtin_amdgcn_s_setprio(0);
    if (s + 1 == nks) break;
    if (s <= nks - 4)
      vm_gate<2 * LPS>();
    else if (s == nks - 3)
      vm_gate<LPS>();
    else
      vm_gate<0>();
    __builtin_amdgcn_sched_barrier(0);
    __builtin_amdgcn_s_barrier();
  }

#pragma unroll
  for (int fm = 0; fm < FM; ++fm) {
#pragma unroll
    for (int r = 0; r < 4; ++r) {
      const int row = m0 + wr * FM * 16 + fm * 16 + 4 * g + r;
#pragma unroll
      for (int fn = 0; fn < FN; ++fn) {
        const int col = n0 + wc * FN * 16 + fn * 16 + c;
        const long idx2 = (long)row * ldc + col;
        float v = acc[fm][fn][r];
        if constexpr (EPI == 0) {
          ((unsigned short*)Cout)[idx2] = f2bf(v);
        } else if constexpr (EPI == 1) {
          ((float*)Cout)[idx2] = v + ((const float*)aux)[idx2];
        } else {
          const float u = bf2f(((const unsigned short*)aux)[idx2]);
          const float sg = v / (1.0f + __expf(-v));
          ((unsigned short*)Cout)[idx2] = f2bf(sg * u);
        }
      }
    }
  }
}

// ---------------- fused gate+up GEMM with in-register SwiGLU ----------------
// Computes G = A@Bg^T and U = A@Bu^T for the same 128x256 tile, then stores
// silu(G)*U (bf16). Shares the A staging between both products: per-half
// staged bytes 806 MB vs 1074 MB for separate dispatches, and the u
// materialization round-trip disappears.
// 512 thr = 8 waves (WM=2 x WN=4), FM=4, FN=4; acc 2x64 f32.
// 3-slot ring x (A 8KB + Bg 16KB + Bu 16KB) = 120 KiB LDS (1 block/CU).
// LPS=5 (A:1, Bg:2, Bu:2). Stage s+2 during compute of s; slot (s+2)%3 ==
// (s-1)%3 whose ds_reads completed before iteration s-1's end barrier
// (compiler-inserted lgkm waits precede the MFMAs) -> same ledger as the
// champion ring-4. Gates: steady vmcnt(5) (s+1 landed, s+2 flying); tail 0.
__global__ __launch_bounds__(512, 1) void gemm_gu_kernel(
    const unsigned short* __restrict__ A, const unsigned short* __restrict__ Bg,
    const unsigned short* __restrict__ Bu, unsigned short* __restrict__ Cout,
    int M, int N, int K, int lda, int ldb, int ldc, int cm, int cn) {
  constexpr int BM = 128, BN = 256;
  constexpr int ASLOT = BM * 32;   // 4096 elems
  constexpr int BSLOT = BN * 32;   // 8192 elems
  __shared__ unsigned short As[3 * ASLOT];
  __shared__ unsigned short Bgs[3 * BSLOT];
  __shared__ unsigned short Bus[3 * BSLOT];

  const int tid = threadIdx.x;
  const int lane = tid & 63, g = lane >> 4, c = lane & 15;
  const int w = tid >> 6, wr = w >> 2, wc = w & 3;

  const int nbn = N / BN;
  const int bid = (int)blockIdx.x;
  const int xcd = bid & 7, idx = bid >> 3;
  const int chn = nbn / cn;
  const int crow = xcd / chn, ccol = xcd % chn;
  const int m0 = (crow * cm + idx / cn) * BM;
  const int n0 = (ccol * cn + idx % cn) * BN;

  const int nks = K >> 5;
  const int srow = tid >> 2;         // 128 rows x 4 lanes
  const int kq8 = (tid & 3) * 8;
  const unsigned short* A_ = A + (long)m0 * lda;
  const unsigned short* Bg_ = Bg + (long)n0 * ldb;
  const unsigned short* Bu_ = Bu + (long)n0 * ldb;

  auto stage = [&](int s) {
    const int slot = s % 3;
    const long kofs = (long)s * 32 + kq8;
    load_lds16(A_ + (long)srow * lda + kofs, &As[slot * ASLOT + tid * 8]);
#pragma unroll
    for (int j = 0; j < 2; ++j)
      load_lds16(Bg_ + (long)(j * 128 + srow) * ldb + kofs,
                 &Bgs[slot * BSLOT + (j * 512 + tid) * 8]);
#pragma unroll
    for (int j = 0; j < 2; ++j)
      load_lds16(Bu_ + (long)(j * 128 + srow) * ldb + kofs,
                 &Bus[slot * BSLOT + (j * 512 + tid) * 8]);
  };

  f32x4 accG[4][4] = {};
  f32x4 accU[4][4] = {};

  stage(0);
  if (nks > 1) stage(1);
  vm_gate<5>();
  __builtin_amdgcn_sched_barrier(0);
  __builtin_amdgcn_s_barrier();

  for (int s = 0; s < nks; ++s) {
    const int slot = s % 3;
    const unsigned short* Ap = &As[slot * ASLOT] + (wr * 64 + c) * 32 + g * 8;
    const unsigned short* Bgp = &Bgs[slot * BSLOT] + (wc * 64 + c) * 32 + g * 8;
    const unsigned short* Bup = &Bus[slot * BSLOT] + (wc * 64 + c) * 32 + g * 8;
    bf16x8 fa[4], fbg[4], fbu[4];
#pragma unroll
    for (int fm = 0; fm < 4; ++fm) fa[fm] = *(const bf16x8*)(Ap + fm * 512);
#pragma unroll
    for (int fn = 0; fn < 4; ++fn) {
      fbg[fn] = *(const bf16x8*)(Bgp + fn * 512);
      fbu[fn] = *(const bf16x8*)(Bup + fn * 512);
    }
    if (s + 2 < nks) stage(s + 2);
    __builtin_amdgcn_s_setprio(1);
#pragma unroll
    for (int fm = 0; fm < 4; ++fm)
#pragma unroll
      for (int fn = 0; fn < 4; ++fn) {
        accG[fm][fn] = __builtin_amdgcn_mfma_f32_16x16x32_bf16(fa[fm], fbg[fn], accG[fm][fn], 0, 0, 0);
        accU[fm][fn] = __builtin_amdgcn_mfma_f32_16x16x32_bf16(fa[fm], fbu[fn], accU[fm][fn], 0, 0, 0);
      }
    __builtin_amdgcn_s_setprio(0);
    if (s + 1 == nks) break;
    if (s + 2 < nks)
      vm_gate<5>();
    else
      vm_gate<0>();
    __builtin_amdgcn_sched_barrier(0);
    __builtin_amdgcn_s_barrier();
  }

#pragma unroll
  for (int fm = 0; fm < 4; ++fm) {
#pragma unroll
    for (int r = 0; r < 4; ++r) {
      const int row = m0 + wr * 64 + fm * 16 + 4 * g + r;
#pragma unroll
      for (int fn = 0; fn < 4; ++fn) {
        const int col = n0 + wc * 64 + fn * 16 + c;
        const float gv = accG[fm][fn][r];
        const float uv = accU[fm][fn][r];
        const float sg = gv / (1.0f + __expf(-gv));
        Cout[(long)row * ldc + col] = f2bf(sg * uv);
      }
    }
  }
}

// ---------------- RoPE tables -----------------------------------------------
__global__ void rope_tables_kernel(float* __restrict__ cost, float* __restrict__ sint) {
  const int idx = blockIdx.x * 256 + threadIdx.x;  // T*64
  const int t = idx >> 6, i = idx & 63;
  const float invf = powf(10000.0f, -(float)i * (1.0f / 64.0f));
  const float ang = (float)t * invf;
  cost[idx] = cosf(ang);
  sint[idx] = sinf(ang);
}

// ---------------- RoPE apply (vectorized 8-wide) on q,k of qkv(bf16) --------
__global__ __launch_bounds__(256) void rope_apply_kernel(
    unsigned short* __restrict__ qkv, const float* __restrict__ cost,
    const float* __restrict__ sint) {
  const long idx = (long)blockIdx.x * 256 + threadIdx.x;  // BT*16*2*8
  const int u = (int)(idx & 7);
  const int h = (int)((idx >> 3) & 15);
  const int qk = (int)((idx >> 7) & 1);
  const long row = idx >> 8;  // 0..BT-1
  const int t = (int)(row & (T_SEQ - 1));
  unsigned short* p = qkv + row * (3 * D_MODEL) + qk * D_MODEL + h * D_HEAD + u * 8;
  u16x8 lo = *(const u16x8*)p;
  u16x8 hi = *(const u16x8*)(p + 64);
  const float4 c0 = *(const float4*)(cost + t * 64 + u * 8);
  const float4 c1 = *(const float4*)(cost + t * 64 + u * 8 + 4);
  const float4 s0 = *(const float4*)(sint + t * 64 + u * 8);
  const float4 s1 = *(const float4*)(sint + t * 64 + u * 8 + 4);
  const float cv[8] = {c0.x, c0.y, c0.z, c0.w, c1.x, c1.y, c1.z, c1.w};
  const float sv[8] = {s0.x, s0.y, s0.z, s0.w, s1.x, s1.y, s1.z, s1.w};
  u16x8 ro, rh;
#pragma unroll
  for (int j = 0; j < 8; ++j) {
    const float a = bf2f(lo[j]);
    const float b = bf2f(hi[j]);
    ro[j] = f2bf(a * cv[j] - b * sv[j]);
    rh[j] = f2bf(b * cv[j] + a * sv[j]);
  }
  *(u16x8*)p = ro;
  *(u16x8*)(p + 64) = rh;
}

// ---------------- V transpose (vectorized): qkv v -> vt [B,H,128,T] ---------
__global__ __launch_bounds__(256) void vtrans_kernel(
    const unsigned short* __restrict__ qkv, unsigned short* __restrict__ vt) {
  __shared__ unsigned short tile[64][68];
  const int tx = threadIdx.x, ty = threadIdx.y;  // [0,16)
  const int t0 = blockIdx.x * 64, d0 = blockIdx.y * 64;
  const int bh = blockIdx.z;  // b*16+h
  const int b = bh >> 4, h = bh & 15;
#pragma unroll
  for (int i = 0; i < 4; ++i) {
    const ushort4 v = *(const ushort4*)(
        qkv + (long)(b * T_SEQ + t0 + ty + 16 * i) * (3 * D_MODEL) + 2 * D_MODEL +
        h * D_HEAD + d0 + tx * 4);
    unsigned short* tr = &tile[ty + 16 * i][tx * 4];
    tr[0] = v.x; tr[1] = v.y; tr[2] = v.z; tr[3] = v.w;
  }
  __syncthreads();
#pragma unroll
  for (int i = 0; i < 4; ++i) {
    const int dd = ty + 16 * i;
    ushort4 o;
    o.x = tile[tx * 4 + 0][dd];
    o.y = tile[tx * 4 + 1][dd];
    o.z = tile[tx * 4 + 2][dd];
    o.w = tile[tx * 4 + 3][dd];
    *(ushort4*)(vt + ((long)bh * D_HEAD + d0 + dd) * T_SEQ + t0 + tx * 4) = o;
  }
}

// ---------------- Flash attention (causal), swapped-QK^T --------------------
__global__ __launch_bounds__(256) void attn_kernel(
    const unsigned short* __restrict__ qkv, const unsigned short* __restrict__ vt,
    unsigned short* __restrict__ ctx) {
  __shared__ unsigned short Ks[2][64 * 128];
  __shared__ unsigned short Vs[2][128 * 64];
  const int h = blockIdx.y, b = blockIdx.z;
  const int tid = threadIdx.x;
  const int w = tid >> 6, lane = tid & 63, g = lane >> 4, c = lane & 15;
  const float scale = 0.08838834764831845f;  // 128^-0.5
  const int srcA = (2 * (g & 1)) * 16 + c;
  const int srcB = srcA + 16;
  const bool hi = (g >> 1) != 0;
  const int bh = b * N_HEADS + h;

  const int ssk = (tid & 15) ^ ((tid >> 4) & 7);
  const int ssv = (tid & 7) ^ ((tid >> 3) & 7);
  const unsigned short* Kg = qkv + (long)b * T_SEQ * 3 * D_MODEL + D_MODEL + (long)h * D_HEAD;
  const unsigned short* Vg = vt + (long)bh * D_HEAD * T_SEQ;

  auto stage = [&](int kv0, int bufi) {
#pragma unroll
    for (int i = 0; i < 4; ++i) {
      const int rowk = i * 16 + (tid >> 4);
      load_lds16(Kg + (long)(kv0 + rowk) * (3 * D_MODEL) + ssk * 8,
                 &Ks[bufi][(i * 256 + tid) * 8]);
    }
#pragma unroll
    for (int i = 0; i < 4; ++i) {
      const int rowv = i * 32 + (tid >> 3);
      load_lds16(Vg + (long)rowv * T_SEQ + kv0 + ssv * 8,
                 &Vs[bufi][(i * 256 + tid) * 8]);
    }
  };

  const int cs7 = c & 7;

  for (int pass = 0; pass < 2; ++pass) {
    const int qt = pass ? (NT - 1 - blockIdx.x) : blockIdx.x;
    const int q = qt * 64 + w * 16 + c;

    bf16x8 fq[4];
    const long rowQ = (long)(b * T_SEQ + q) * (3 * D_MODEL) + h * D_HEAD;
#pragma unroll
    for (int ks = 0; ks < 4; ++ks)
      fq[ks] = *(const bf16x8*)(qkv + rowQ + ks * 32 + g * 8);

    f32x4 o[8] = {};
    float mrun = -INFINITY, ell = 0.0f;

    stage(0, 0);
    asm volatile("s_waitcnt vmcnt(0)" ::: "memory");
    __syncthreads();
    int buf = 0;

    for (int kt = 0; kt <= qt; ++kt) {
      const int kv0 = kt * 64;
      if (kt < qt) stage(kv0 + 64, buf ^ 1);

      f32x4 s[4] = {};
      __builtin_amdgcn_s_setprio(1);
#pragma unroll
      for (int fm = 0; fm < 4; ++fm) {
        const unsigned short* kr = &Ks[buf][(fm * 16 + c) * 128];
#pragma unroll
        for (int ks = 0; ks < 4; ++ks) {
          bf16x8 ak = *(const bf16x8*)(kr + ((ks * 4 + g) ^ cs7) * 8);
          s[fm] = __builtin_amdgcn_mfma_f32_16x16x32_bf16(ak, fq[ks], s[fm], 0, 0, 0);
        }
      }
      __builtin_amdgcn_s_setprio(0);
      float pmax = -INFINITY;
      const bool diag = (kt == qt);
#pragma unroll
      for (int fm = 0; fm < 4; ++fm)
#pragma unroll
        for (int r = 0; r < 4; ++r) {
          float sv = s[fm][r] * scale;
          if (diag) {
            const int kp = kv0 + fm * 16 + 4 * g + r;
            if (kp > q) sv = -INFINITY;
          }
          s[fm][r] = sv;
          pmax = fmaxf(pmax, sv);
        }
      pmax = fmaxf(pmax, __shfl_xor(pmax, 16));
      pmax = fmaxf(pmax, __shfl_xor(pmax, 32));
      const float mnew = fmaxf(mrun, pmax);
      const float resc = __expf(mrun - mnew);
      mrun = mnew;
      float rowsum = 0.0f;
#pragma unroll
      for (int fm = 0; fm < 4; ++fm)
#pragma unroll
        for (int r = 0; r < 4; ++r) {
          const float p = __expf(s[fm][r] - mnew);
          s[fm][r] = p;
          rowsum += p;
        }
      rowsum += __shfl_xor(rowsum, 16);
      rowsum += __shfl_xor(rowsum, 32);
      ell = ell * resc + rowsum;
#pragma unroll
      for (int fm = 0; fm < 8; ++fm) o[fm] *= resc;

      bf16x8 pb[2];
#pragma unroll
      for (int k2 = 0; k2 < 2; ++k2) {
        float va[4], vb[4];
#pragma unroll
        for (int r = 0; r < 4; ++r) {
          const float t0 = __shfl(s[k2 * 2][r], srcA);
          const float t1 = __shfl(s[k2 * 2 + 1][r], srcA);
          va[r] = hi ? t1 : t0;
          const float u0 = __shfl(s[k2 * 2][r], srcB);
          const float u1 = __shfl(s[k2 * 2 + 1][r], srcB);
          vb[r] = hi ? u1 : u0;
        }
        bf16x8 pv;
        pv[0] = (__bf16)va[0]; pv[1] = (__bf16)va[1];
        pv[2] = (__bf16)va[2]; pv[3] = (__bf16)va[3];
        pv[4] = (__bf16)vb[0]; pv[5] = (__bf16)vb[1];
        pv[6] = (__bf16)vb[2]; pv[7] = (__bf16)vb[3];
        pb[k2] = pv;
      }
      __builtin_amdgcn_s_setprio(1);
#pragma unroll
      for (int fm = 0; fm < 8; ++fm) {
        const unsigned short* vr = &Vs[buf][(fm * 16 + c) * 64];
#pragma unroll
        for (int k2 = 0; k2 < 2; ++k2) {
          bf16x8 av = *(const bf16x8*)(vr + ((k2 * 4 + g) ^ cs7) * 8);
          o[fm] = __builtin_amdgcn_mfma_f32_16x16x32_bf16(av, pb[k2], o[fm], 0, 0, 0);
        }
      }
      __builtin_amdgcn_s_setprio(0);
      asm volatile("s_waitcnt vmcnt(0)" ::: "memory");
      __syncthreads();
      buf ^= 1;
    }

    const float inv = 1.0f / ell;
    unsigned short* outp = ctx + (long)(b * T_SEQ + q) * D_MODEL + h * D_HEAD;
#pragma unroll
    for (int fm = 0; fm < 8; ++fm) {
      ushort4 pk;
      pk.x = f2bf(o[fm][0] * inv);
      pk.y = f2bf(o[fm][1] * inv);
      pk.z = f2bf(o[fm][2] * inv);
      pk.w = f2bf(o[fm][3] * inv);
      *(ushort4*)(outp + fm * 16 + 4 * g) = pk;
    }
  }
}

// ---------------------------------------------------------------------------
extern "C" void kernel_launch(void* const* d_in, const int* in_sizes, int n_in,
                              void* d_out, int out_size, void* d_ws, size_t ws_size,
                              hipStream_t stream) {
  const float* x = (const float*)d_in[0];
  const float* w_qkv = (const float*)d_in[1];
  const float* w_out = (const float*)d_in[2];
  const float* g1 = (const float*)d_in[3];
  const float* g2 = (const float*)d_in[4];
  const float* w_g = (const float*)d_in[5];
  const float* w_u = (const float*)d_in[6];
  const float* w_o = (const float*)d_in[7];
  float* out = (float*)d_out;

  char* ws = (char*)d_ws;
  size_t off = 0;
  auto take = [&](size_t bytes) {
    char* p = ws + off;
    off += (bytes + 255) & ~(size_t)255;
    return p;
  };

  char* Wreg = take((size_t)3 * D_FF * D_MODEL * 2);  // 100.66 MB
  unsigned short* wTqkv = (unsigned short*)Wreg;
  unsigned short* wTout = (unsigned short*)(Wreg + (size_t)3 * D_MODEL * D_MODEL * 2);
  unsigned short* wTg = (unsigned short*)Wreg;
  unsigned short* wTu = (unsigned short*)(Wreg + (size_t)D_FF * D_MODEL * 2);
  unsigned short* wTo = (unsigned short*)(Wreg + (size_t)2 * D_FF * D_MODEL * 2);

  const size_t qkv_b = (size_t)BT * 3 * D_MODEL * 2;
  const size_t vt_b = (size_t)B_SZ * N_HEADS * D_HEAD * T_SEQ * 2;
  const size_t ctx_b = (size_t)BT * D_MODEL * 2;
  char* AR = take(qkv_b + vt_b + ctx_b);  // 83.9 MB
  unsigned short* qkvb = (unsigned short*)AR;
  unsigned short* vtb = (unsigned short*)(AR + qkv_b);
  unsigned short* ctxb = (unsigned short*)(AR + qkv_b + vt_b);
  unsigned short* gbuf0 = (unsigned short*)AR;                                   // 33.6 MB
  unsigned short* gbuf1 = (unsigned short*)(AR + (size_t)BT * (D_FF / 2) * 2);   // 33.6 MB

  float* x1 = (float*)take((size_t)BT * D_MODEL * 4);
  unsigned short* hb = (unsigned short*)take((size_t)BT * D_MODEL * 2);
  float* cost = (float*)take((size_t)T_SEQ * 64 * 4);
  float* sint = (float*)take((size_t)T_SEQ * 64 * 4);

  const dim3 tb(16, 16);

  // ---- phase A: attention ----
  transpose_cast_kernel<<<dim3(3 * D_MODEL / 64, D_MODEL / 64), tb, 0, stream>>>(w_qkv, wTqkv, D_MODEL, 3 * D_MODEL);
  transpose_cast_kernel<<<dim3(D_MODEL / 64, D_MODEL / 64), tb, 0, stream>>>(w_out, wTout, D_MODEL, D_MODEL);
  rope_tables_kernel<<<T_SEQ * 64 / 256, 256, 0, stream>>>(cost, sint);

  rmsnorm_cast_kernel<<<BT, 256, 0, stream>>>(x, g1, hb);
  // QKV: 256^2; nbm=16, nbn=24 -> 384 blocks, XCD rect 8x6
  gemm_ks_kernel<0, 2, 4, 8, 4><<<384, 512, 0, stream>>>(
      hb, wTqkv, qkvb, nullptr, nullptr, BT, 3 * D_MODEL, D_MODEL, D_MODEL, D_MODEL, 3 * D_MODEL, 8, 6);
  rope_apply_kernel<<<(BT * N_HEADS * 2 * 8) / 256, 256, 0, stream>>>(qkvb, cost, sint);
  vtrans_kernel<<<dim3(T_SEQ / 64, D_HEAD / 64, B_SZ * N_HEADS), tb, 0, stream>>>(qkvb, vtb);
  attn_kernel<<<dim3(NT / 2, N_HEADS, B_SZ), 256, 0, stream>>>(qkvb, vtb, ctxb);
  // out-proj: 256x128; 256 blocks, rect 8x4
  gemm_ks_kernel<1, 4, 2, 4, 4><<<256, 512, 0, stream>>>(
      ctxb, wTout, x1, x, nullptr, BT, D_MODEL, D_MODEL, D_MODEL, D_MODEL, D_MODEL, 8, 4);

  // ---- phase B: MLP ----
  transpose_cast_kernel<<<dim3(D_FF / 64, D_MODEL / 64), tb, 0, stream>>>(w_g, wTg, D_MODEL, D_FF);
  transpose_cast_kernel<<<dim3(D_FF / 64, D_MODEL / 64), tb, 0, stream>>>(w_u, wTu, D_MODEL, D_FF);
  transpose_cast_kernel<<<dim3(D_MODEL / 64, D_FF / 64), tb, 0, stream>>>(w_o, wTo, D_FF, D_MODEL);
  rmsnorm_cast_kernel<<<BT, 256, 0, stream>>>(x1, g2, hb);

  const int NH = D_FF / 2;  // 4096 ff-columns per half
  for (int half = 0; half < 2; ++half) {
    const unsigned short* wTu_h = wTu + (size_t)half * NH * D_MODEL;
    const unsigned short* wTg_h = wTg + (size_t)half * NH * D_MODEL;
    unsigned short* gb = half ? gbuf1 : gbuf0;
    // fused gate+up with in-register SwiGLU: gb = silu(h@wTg_h) * (h@wTu_h)
    // nbm=32, nbn=16 -> 512 blocks, XCD rect 8x8
    gemm_gu_kernel<<<512, 512, 0, stream>>>(
        hb, wTg_h, wTu_h, gb, BT, NH, D_MODEL, D_MODEL, D_MODEL, NH, 8, 8);
  }
  // down: single K=8192 dispatch, A = gbuf0 (k<4096) / gbuf1 (k>=4096)
  gemm_ks_kernel<1, 4, 2, 4, 4, true><<<256, 512, 0, stream>>>(
      gbuf0, wTo, out, x1, gbuf1, BT, D_MODEL, D_FF, NH, D_FF, D_MODEL, 8, 4);
}

// Round 15
// 779.504 us; speedup vs baseline: 1.0004x; 1.0004x over previous
//
#include <hip/hip_runtime.h>

typedef __bf16 bf16x8 __attribute__((ext_vector_type(8)));
typedef float f32x4 __attribute__((ext_vector_type(4)));
typedef unsigned short u16x8 __attribute__((ext_vector_type(8)));

#define B_SZ 2
#define T_SEQ 2048
#define D_MODEL 2048
#define N_HEADS 16
#define D_HEAD 128
#define D_FF 8192
#define BT (B_SZ * T_SEQ)
#define NT (T_SEQ / 64)

__device__ __forceinline__ unsigned short f2bf(float f) {
  unsigned int u = __builtin_bit_cast(unsigned int, f);
  u += 0x7FFFu + ((u >> 16) & 1u);
  return (unsigned short)(u >> 16);
}
__device__ __forceinline__ float bf2f(unsigned short h) {
  unsigned int u = ((unsigned int)h) << 16;
  return __builtin_bit_cast(float, u);
}

__device__ __forceinline__ void load_lds16(const void* g, void* l) {
  __builtin_amdgcn_global_load_lds(
      (const __attribute__((address_space(1))) unsigned int*)g,
      (__attribute__((address_space(3))) unsigned int*)l, 16, 0, 0);
}

template <int N>
__device__ __forceinline__ void vm_gate() {
  if constexpr (N <= 0)
    asm volatile("s_waitcnt vmcnt(0)" ::: "memory");
  else if constexpr (N == 2)
    asm volatile("s_waitcnt vmcnt(2)" ::: "memory");
  else if constexpr (N == 3)
    asm volatile("s_waitcnt vmcnt(3)" ::: "memory");
  else if constexpr (N == 4)
    asm volatile("s_waitcnt vmcnt(4)" ::: "memory");
  else if constexpr (N == 6)
    asm volatile("s_waitcnt vmcnt(6)" ::: "memory");
  else
    asm volatile("s_waitcnt vmcnt(8)" ::: "memory");
}

// ---------------- transpose + cast: in fp32 [R][C] -> out bf16 [C][R] -------
__global__ __launch_bounds__(256) void transpose_cast_kernel(
    const float* __restrict__ in, unsigned short* __restrict__ out, int R, int C) {
  __shared__ float tile[64][65];
  const int tx = threadIdx.x, ty = threadIdx.y;  // [0,16)
  const int c0 = blockIdx.x * 64, r0 = blockIdx.y * 64;
#pragma unroll
  for (int i = 0; i < 4; ++i) {
    const float4 v = *(const float4*)(in + (long)(r0 + ty + 16 * i) * C + c0 + tx * 4);
    float* tr = &tile[ty + 16 * i][tx * 4];
    tr[0] = v.x; tr[1] = v.y; tr[2] = v.z; tr[3] = v.w;
  }
  __syncthreads();
#pragma unroll
  for (int i = 0; i < 4; ++i) {
    const int cc = ty + 16 * i;
    ushort4 o;
    o.x = f2bf(tile[tx * 4 + 0][cc]);
    o.y = f2bf(tile[tx * 4 + 1][cc]);
    o.z = f2bf(tile[tx * 4 + 2][cc]);
    o.w = f2bf(tile[tx * 4 + 3][cc]);
    *(ushort4*)(out + (long)(c0 + cc) * R + r0 + tx * 4) = o;
  }
}

// ---------------- RMSNorm fp32 row -> bf16 ----------------------------------
__global__ __launch_bounds__(256) void rmsnorm_cast_kernel(
    const float* __restrict__ x, const float* __restrict__ gw,
    unsigned short* __restrict__ out) {
  const int row = blockIdx.x;
  const int tid = threadIdx.x;
  const float* xr = x + (long)row * D_MODEL;
  float4 a = *(const float4*)(xr + tid * 8);
  float4 b = *(const float4*)(xr + tid * 8 + 4);
  float ss = a.x * a.x + a.y * a.y + a.z * a.z + a.w * a.w +
             b.x * b.x + b.y * b.y + b.z * b.z + b.w * b.w;
#pragma unroll
  for (int d = 1; d < 64; d <<= 1) ss += __shfl_xor(ss, d);
  __shared__ float part[4];
  if ((tid & 63) == 0) part[tid >> 6] = ss;
  __syncthreads();
  ss = part[0] + part[1] + part[2] + part[3];
  const float rs = rsqrtf(ss * (1.0f / D_MODEL) + 1e-6f);
  float4 g0 = *(const float4*)(gw + tid * 8);
  float4 g1 = *(const float4*)(gw + tid * 8 + 4);
  ushort4 o0, o1;
  o0.x = f2bf(a.x * rs * g0.x); o0.y = f2bf(a.y * rs * g0.y);
  o0.z = f2bf(a.z * rs * g0.z); o0.w = f2bf(a.w * rs * g0.w);
  o1.x = f2bf(b.x * rs * g1.x); o1.y = f2bf(b.y * rs * g1.y);
  o1.z = f2bf(b.z * rs * g1.z); o1.w = f2bf(b.w * rs * g1.w);
  unsigned short* op = out + (long)row * D_MODEL + tid * 8;
  *(ushort4*)op = o0;
  *(ushort4*)(op + 4) = o1;
}

// ---------------- k-slice-ring pipelined GEMM (champion schedule) -----------
template <int EPI, int WM, int WN, int FM, int FN, bool DUALA = false>
__global__ __launch_bounds__(WM * WN * 64, 2) void gemm_ks_kernel(
    const unsigned short* __restrict__ A, const unsigned short* __restrict__ Bt,
    void* __restrict__ Cout, const void* __restrict__ aux,
    const unsigned short* __restrict__ A2,
    int M, int N, int K, int lda, int ldb, int ldc, int cm, int cn) {
  constexpr int THREADS = WM * WN * 64;
  constexpr int BM = WM * FM * 16;
  constexpr int BN = WN * FN * 16;
  constexpr int ASLOT = BM * 32;
  constexpr int BSLOT = BN * 32;
  constexpr int RPR = THREADS / 4;
  constexpr int LPS = BM / RPR + BN / RPR;  // loads per slice per thread
  __shared__ unsigned short As[4 * ASLOT];
  __shared__ unsigned short Bs[4 * BSLOT];

  const int tid = threadIdx.x;
  const int lane = tid & 63, g = lane >> 4, c = lane & 15;
  const int w = tid >> 6, wr = w / WN, wc = w % WN;

  const int nbn = N / BN;
  const int bid = (int)blockIdx.x;
  const int xcd = bid & 7, idx = bid >> 3;
  const int chn = nbn / cn;
  const int crow = xcd / chn, ccol = xcd % chn;
  const int mr = idx / cn, nc2 = idx % cn;
  const int m0 = (crow * cm + mr) * BM;
  const int n0 = (ccol * cn + nc2) * BN;

  const int nks = K >> 5;
  const int srow = tid >> 2;
  const int kq8 = (tid & 3) * 8;
  const unsigned short* A_ = A + (long)m0 * lda;
  const unsigned short* A2_ = DUALA ? (A2 + (long)m0 * lda) : nullptr;
  const unsigned short* B_ = Bt + (long)n0 * ldb;

  auto stage = [&](int s) {
    const int slot = s & 3;
    const long k32 = (long)s * 32;
    const unsigned short* Ab;
    long akofs;
    if constexpr (DUALA) {
      const int khalf = K >> 1;
      const bool lo = k32 < khalf;
      Ab = lo ? A_ : A2_;
      akofs = (lo ? k32 : k32 - khalf) + kq8;
    } else {
      Ab = A_;
      akofs = k32 + kq8;
    }
    const long bkofs = k32 + kq8;
#pragma unroll
    for (int j = 0; j < BM / RPR; ++j)
      load_lds16(Ab + (long)(j * RPR + srow) * lda + akofs,
                 &As[slot * ASLOT + (j * THREADS + tid) * 8]);
#pragma unroll
    for (int j = 0; j < BN / RPR; ++j)
      load_lds16(B_ + (long)(j * RPR + srow) * ldb + bkofs,
                 &Bs[slot * BSLOT + (j * THREADS + tid) * 8]);
  };

  f32x4 acc[FM][FN] = {};

  stage(0);
  if (nks > 1) stage(1);
  if (nks > 2) stage(2);
  vm_gate<2 * LPS>();
  __builtin_amdgcn_sched_barrier(0);
  __builtin_amdgcn_s_barrier();

  for (int s = 0; s < nks; ++s) {
    const int slot = s & 3;
    const unsigned short* Ap = &As[slot * ASLOT] + (wr * FM * 16 + c) * 32 + g * 8;
    const unsigned short* Bp = &Bs[slot * BSLOT] + (wc * FN * 16 + c) * 32 + g * 8;
    bf16x8 fa[FM], fb[FN];
#pragma unroll
    for (int fm = 0; fm < FM; ++fm) fa[fm] = *(const bf16x8*)(Ap + fm * 512);
#pragma unroll
    for (int fn = 0; fn < FN; ++fn) fb[fn] = *(const bf16x8*)(Bp + fn * 512);
    if (s + 3 < nks) stage(s + 3);
    __builtin_amdgcn_s_setprio(1);
#pragma unroll
    for (int fm = 0; fm < FM; ++fm)
#pragma unroll
      for (int fn = 0; fn < FN; ++fn)
        acc[fm][fn] = __builtin_amdgcn_mfma_f32_16x16x32_bf16(fa[fm], fb[fn], acc[fm][fn], 0, 0, 0);
    __builtin_amdgcn_s_setprio(0);
    if (s + 1 == nks) break;
    if (s <= nks - 4)
      vm_gate<2 * LPS>();
    else if (s == nks - 3)
      vm_gate<LPS>();
    else
      vm_gate<0>();
    __builtin_amdgcn_sched_barrier(0);
    __builtin_amdgcn_s_barrier();
  }

#pragma unroll
  for (int fm = 0; fm < FM; ++fm) {
#pragma unroll
    for (int r = 0; r < 4; ++r) {
      const int row = m0 + wr * FM * 16 + fm * 16 + 4 * g + r;
#pragma unroll
      for (int fn = 0; fn < FN; ++fn) {
        const int col = n0 + wc * FN * 16 + fn * 16 + c;
        const long idx2 = (long)row * ldc + col;
        float v = acc[fm][fn][r];
        if constexpr (EPI == 0) {
          ((unsigned short*)Cout)[idx2] = f2bf(v);
        } else if constexpr (EPI == 1) {
          ((float*)Cout)[idx2] = v + ((const float*)aux)[idx2];
        } else {
          const float u = bf2f(((const unsigned short*)aux)[idx2]);
          const float sg = v / (1.0f + __expf(-v));
          ((unsigned short*)Cout)[idx2] = f2bf(sg * u);
        }
      }
    }
  }
}

// ---------------- RoPE tables -----------------------------------------------
__global__ void rope_tables_kernel(float* __restrict__ cost, float* __restrict__ sint) {
  const int idx = blockIdx.x * 256 + threadIdx.x;  // T*64
  const int t = idx >> 6, i = idx & 63;
  const float invf = powf(10000.0f, -(float)i * (1.0f / 64.0f));
  const float ang = (float)t * invf;
  cost[idx] = cosf(ang);
  sint[idx] = sinf(ang);
}

// ---------------- RoPE apply (vectorized 8-wide) on q,k of qkv(bf16) --------
__global__ __launch_bounds__(256) void rope_apply_kernel(
    unsigned short* __restrict__ qkv, const float* __restrict__ cost,
    const float* __restrict__ sint) {
  const long idx = (long)blockIdx.x * 256 + threadIdx.x;  // BT*16*2*8
  const int u = (int)(idx & 7);
  const int h = (int)((idx >> 3) & 15);
  const int qk = (int)((idx >> 7) & 1);
  const long row = idx >> 8;  // 0..BT-1
  const int t = (int)(row & (T_SEQ - 1));
  unsigned short* p = qkv + row * (3 * D_MODEL) + qk * D_MODEL + h * D_HEAD + u * 8;
  u16x8 lo = *(const u16x8*)p;
  u16x8 hi = *(const u16x8*)(p + 64);
  const float4 c0 = *(const float4*)(cost + t * 64 + u * 8);
  const float4 c1 = *(const float4*)(cost + t * 64 + u * 8 + 4);
  const float4 s0 = *(const float4*)(sint + t * 64 + u * 8);
  const float4 s1 = *(const float4*)(sint + t * 64 + u * 8 + 4);
  const float cv[8] = {c0.x, c0.y, c0.z, c0.w, c1.x, c1.y, c1.z, c1.w};
  const float sv[8] = {s0.x, s0.y, s0.z, s0.w, s1.x, s1.y, s1.z, s1.w};
  u16x8 ro, rh;
#pragma unroll
  for (int j = 0; j < 8; ++j) {
    const float a = bf2f(lo[j]);
    const float b = bf2f(hi[j]);
    ro[j] = f2bf(a * cv[j] - b * sv[j]);
    rh[j] = f2bf(b * cv[j] + a * sv[j]);
  }
  *(u16x8*)p = ro;
  *(u16x8*)(p + 64) = rh;
}

// ---------------- V transpose (vectorized): qkv v -> vt [B,H,128,T] ---------
__global__ __launch_bounds__(256) void vtrans_kernel(
    const unsigned short* __restrict__ qkv, unsigned short* __restrict__ vt) {
  __shared__ unsigned short tile[64][68];
  const int tx = threadIdx.x, ty = threadIdx.y;  // [0,16)
  const int t0 = blockIdx.x * 64, d0 = blockIdx.y * 64;
  const int bh = blockIdx.z;  // b*16+h
  const int b = bh >> 4, h = bh & 15;
#pragma unroll
  for (int i = 0; i < 4; ++i) {
    const ushort4 v = *(const ushort4*)(
        qkv + (long)(b * T_SEQ + t0 + ty + 16 * i) * (3 * D_MODEL) + 2 * D_MODEL +
        h * D_HEAD + d0 + tx * 4);
    unsigned short* tr = &tile[ty + 16 * i][tx * 4];
    tr[0] = v.x; tr[1] = v.y; tr[2] = v.z; tr[3] = v.w;
  }
  __syncthreads();
#pragma unroll
  for (int i = 0; i < 4; ++i) {
    const int dd = ty + 16 * i;
    ushort4 o;
    o.x = tile[tx * 4 + 0][dd];
    o.y = tile[tx * 4 + 1][dd];
    o.z = tile[tx * 4 + 2][dd];
    o.w = tile[tx * 4 + 3][dd];
    *(ushort4*)(vt + ((long)bh * D_HEAD + d0 + dd) * T_SEQ + t0 + tx * 4) = o;
  }
}

// ---------------- Flash attention (causal), swapped-QK^T --------------------
// + defer-max (T13, THR=8): skip the O/ell rescale when the tile max didn't
// grow past mrun+8; P then bounded by e^8 (bf16/f32-safe; same normalization).
__global__ __launch_bounds__(256) void attn_kernel(
    const unsigned short* __restrict__ qkv, const unsigned short* __restrict__ vt,
    unsigned short* __restrict__ ctx) {
  __shared__ unsigned short Ks[2][64 * 128];
  __shared__ unsigned short Vs[2][128 * 64];
  const int h = blockIdx.y, b = blockIdx.z;
  const int tid = threadIdx.x;
  const int w = tid >> 6, lane = tid & 63, g = lane >> 4, c = lane & 15;
  const float scale = 0.08838834764831845f;  // 128^-0.5
  const int srcA = (2 * (g & 1)) * 16 + c;
  const int srcB = srcA + 16;
  const bool hi = (g >> 1) != 0;
  const int bh = b * N_HEADS + h;

  const int ssk = (tid & 15) ^ ((tid >> 4) & 7);
  const int ssv = (tid & 7) ^ ((tid >> 3) & 7);
  const unsigned short* Kg = qkv + (long)b * T_SEQ * 3 * D_MODEL + D_MODEL + (long)h * D_HEAD;
  const unsigned short* Vg = vt + (long)bh * D_HEAD * T_SEQ;

  auto stage = [&](int kv0, int bufi) {
#pragma unroll
    for (int i = 0; i < 4; ++i) {
      const int rowk = i * 16 + (tid >> 4);
      load_lds16(Kg + (long)(kv0 + rowk) * (3 * D_MODEL) + ssk * 8,
                 &Ks[bufi][(i * 256 + tid) * 8]);
    }
#pragma unroll
    for (int i = 0; i < 4; ++i) {
      const int rowv = i * 32 + (tid >> 3);
      load_lds16(Vg + (long)rowv * T_SEQ + kv0 + ssv * 8,
                 &Vs[bufi][(i * 256 + tid) * 8]);
    }
  };

  const int cs7 = c & 7;

  for (int pass = 0; pass < 2; ++pass) {
    const int qt = pass ? (NT - 1 - blockIdx.x) : blockIdx.x;
    const int q = qt * 64 + w * 16 + c;

    bf16x8 fq[4];
    const long rowQ = (long)(b * T_SEQ + q) * (3 * D_MODEL) + h * D_HEAD;
#pragma unroll
    for (int ks = 0; ks < 4; ++ks)
      fq[ks] = *(const bf16x8*)(qkv + rowQ + ks * 32 + g * 8);

    f32x4 o[8] = {};
    float mrun = -INFINITY, ell = 0.0f;

    stage(0, 0);
    asm volatile("s_waitcnt vmcnt(0)" ::: "memory");
    __syncthreads();
    int buf = 0;

    for (int kt = 0; kt <= qt; ++kt) {
      const int kv0 = kt * 64;
      if (kt < qt) stage(kv0 + 64, buf ^ 1);

      f32x4 s[4] = {};
      __builtin_amdgcn_s_setprio(1);
#pragma unroll
      for (int fm = 0; fm < 4; ++fm) {
        const unsigned short* kr = &Ks[buf][(fm * 16 + c) * 128];
#pragma unroll
        for (int ks = 0; ks < 4; ++ks) {
          bf16x8 ak = *(const bf16x8*)(kr + ((ks * 4 + g) ^ cs7) * 8);
          s[fm] = __builtin_amdgcn_mfma_f32_16x16x32_bf16(ak, fq[ks], s[fm], 0, 0, 0);
        }
      }
      __builtin_amdgcn_s_setprio(0);
      float pmax = -INFINITY;
      const bool diag = (kt == qt);
#pragma unroll
      for (int fm = 0; fm < 4; ++fm)
#pragma unroll
        for (int r = 0; r < 4; ++r) {
          float sv = s[fm][r] * scale;
          if (diag) {
            const int kp = kv0 + fm * 16 + 4 * g + r;
            if (kp > q) sv = -INFINITY;
          }
          s[fm][r] = sv;
          pmax = fmaxf(pmax, sv);
        }
      pmax = fmaxf(pmax, __shfl_xor(pmax, 16));
      pmax = fmaxf(pmax, __shfl_xor(pmax, 32));
      // defer-max: only rescale when the tile max grew past mrun + 8
      if (!__all(pmax <= mrun + 8.0f)) {
        const float mnew = fmaxf(mrun, pmax);
        const float resc = __expf(mrun - mnew);
        ell *= resc;
#pragma unroll
        for (int fm = 0; fm < 8; ++fm) o[fm] *= resc;
        mrun = mnew;
      }
      float rowsum = 0.0f;
#pragma unroll
      for (int fm = 0; fm < 4; ++fm)
#pragma unroll
        for (int r = 0; r < 4; ++r) {
          const float p = __expf(s[fm][r] - mrun);
          s[fm][r] = p;
          rowsum += p;
        }
      rowsum += __shfl_xor(rowsum, 16);
      rowsum += __shfl_xor(rowsum, 32);
      ell += rowsum;

      bf16x8 pb[2];
#pragma unroll
      for (int k2 = 0; k2 < 2; ++k2) {
        float va[4], vb[4];
#pragma unroll
        for (int r = 0; r < 4; ++r) {
          const float t0 = __shfl(s[k2 * 2][r], srcA);
          const float t1 = __shfl(s[k2 * 2 + 1][r], srcA);
          va[r] = hi ? t1 : t0;
          const float u0 = __shfl(s[k2 * 2][r], srcB);
          const float u1 = __shfl(s[k2 * 2 + 1][r], srcB);
          vb[r] = hi ? u1 : u0;
        }
        bf16x8 pv;
        pv[0] = (__bf16)va[0]; pv[1] = (__bf16)va[1];
        pv[2] = (__bf16)va[2]; pv[3] = (__bf16)va[3];
        pv[4] = (__bf16)vb[0]; pv[5] = (__bf16)vb[1];
        pv[6] = (__bf16)vb[2]; pv[7] = (__bf16)vb[3];
        pb[k2] = pv;
      }
      __builtin_amdgcn_s_setprio(1);
#pragma unroll
      for (int fm = 0; fm < 8; ++fm) {
        const unsigned short* vr = &Vs[buf][(fm * 16 + c) * 64];
#pragma unroll
        for (int k2 = 0; k2 < 2; ++k2) {
          bf16x8 av = *(const bf16x8*)(vr + ((k2 * 4 + g) ^ cs7) * 8);
          o[fm] = __builtin_amdgcn_mfma_f32_16x16x32_bf16(av, pb[k2], o[fm], 0, 0, 0);
        }
      }
      __builtin_amdgcn_s_setprio(0);
      asm volatile("s_waitcnt vmcnt(0)" ::: "memory");
      __syncthreads();
      buf ^= 1;
    }

    const float inv = 1.0f / ell;
    unsigned short* outp = ctx + (long)(b * T_SEQ + q) * D_MODEL + h * D_HEAD;
#pragma unroll
    for (int fm = 0; fm < 8; ++fm) {
      ushort4 pk;
      pk.x = f2bf(o[fm][0] * inv);
      pk.y = f2bf(o[fm][1] * inv);
      pk.z = f2bf(o[fm][2] * inv);
      pk.w = f2bf(o[fm][3] * inv);
      *(ushort4*)(outp + fm * 16 + 4 * g) = pk;
    }
  }
}

// ---------------------------------------------------------------------------
// Workspace (~236 MB, aliased):
//   Wreg 100.7 : A = wTqkv(25.2)+wTout(8.4); B = wTg+wTu+wTo (33.6 each)
//   AR    83.9 : A = qkvb(50.3)+vtb(16.8)+ctxb(16.8); B = gbuf0(33.6)+gbuf1(33.6)
//   x1    33.6 (fp32), hb 16.8, tables 1.0
extern "C" void kernel_launch(void* const* d_in, const int* in_sizes, int n_in,
                              void* d_out, int out_size, void* d_ws, size_t ws_size,
                              hipStream_t stream) {
  const float* x = (const float*)d_in[0];
  const float* w_qkv = (const float*)d_in[1];
  const float* w_out = (const float*)d_in[2];
  const float* g1 = (const float*)d_in[3];
  const float* g2 = (const float*)d_in[4];
  const float* w_g = (const float*)d_in[5];
  const float* w_u = (const float*)d_in[6];
  const float* w_o = (const float*)d_in[7];
  float* out = (float*)d_out;

  char* ws = (char*)d_ws;
  size_t off = 0;
  auto take = [&](size_t bytes) {
    char* p = ws + off;
    off += (bytes + 255) & ~(size_t)255;
    return p;
  };

  char* Wreg = take((size_t)3 * D_FF * D_MODEL * 2);  // 100.66 MB
  unsigned short* wTqkv = (unsigned short*)Wreg;
  unsigned short* wTout = (unsigned short*)(Wreg + (size_t)3 * D_MODEL * D_MODEL * 2);
  unsigned short* wTg = (unsigned short*)Wreg;
  unsigned short* wTu = (unsigned short*)(Wreg + (size_t)D_FF * D_MODEL * 2);
  unsigned short* wTo = (unsigned short*)(Wreg + (size_t)2 * D_FF * D_MODEL * 2);

  const size_t qkv_b = (size_t)BT * 3 * D_MODEL * 2;
  const size_t vt_b = (size_t)B_SZ * N_HEADS * D_HEAD * T_SEQ * 2;
  const size_t ctx_b = (size_t)BT * D_MODEL * 2;
  char* AR = take(qkv_b + vt_b + ctx_b);  // 83.9 MB
  unsigned short* qkvb = (unsigned short*)AR;
  unsigned short* vtb = (unsigned short*)(AR + qkv_b);
  unsigned short* ctxb = (unsigned short*)(AR + qkv_b + vt_b);
  unsigned short* gbuf0 = (unsigned short*)AR;                                   // 33.6 MB
  unsigned short* gbuf1 = (unsigned short*)(AR + (size_t)BT * (D_FF / 2) * 2);   // 33.6 MB

  float* x1 = (float*)take((size_t)BT * D_MODEL * 4);
  unsigned short* hb = (unsigned short*)take((size_t)BT * D_MODEL * 2);
  float* cost = (float*)take((size_t)T_SEQ * 64 * 4);
  float* sint = (float*)take((size_t)T_SEQ * 64 * 4);

  const dim3 tb(16, 16);

  // ---- phase A: attention ----
  transpose_cast_kernel<<<dim3(3 * D_MODEL / 64, D_MODEL / 64), tb, 0, stream>>>(w_qkv, wTqkv, D_MODEL, 3 * D_MODEL);
  transpose_cast_kernel<<<dim3(D_MODEL / 64, D_MODEL / 64), tb, 0, stream>>>(w_out, wTout, D_MODEL, D_MODEL);
  rope_tables_kernel<<<T_SEQ * 64 / 256, 256, 0, stream>>>(cost, sint);

  rmsnorm_cast_kernel<<<BT, 256, 0, stream>>>(x, g1, hb);
  // QKV: 256^2; nbm=16, nbn=24 -> 384 blocks, XCD rect 8x6
  gemm_ks_kernel<0, 2, 4, 8, 4><<<384, 512, 0, stream>>>(
      hb, wTqkv, qkvb, nullptr, nullptr, BT, 3 * D_MODEL, D_MODEL, D_MODEL, D_MODEL, 3 * D_MODEL, 8, 6);
  rope_apply_kernel<<<(BT * N_HEADS * 2 * 8) / 256, 256, 0, stream>>>(qkvb, cost, sint);
  vtrans_kernel<<<dim3(T_SEQ / 64, D_HEAD / 64, B_SZ * N_HEADS), tb, 0, stream>>>(qkvb, vtb);
  attn_kernel<<<dim3(NT / 2, N_HEADS, B_SZ), 256, 0, stream>>>(qkvb, vtb, ctxb);
  // out-proj: 256x128; 256 blocks, rect 8x4
  gemm_ks_kernel<1, 4, 2, 4, 4><<<256, 512, 0, stream>>>(
      ctxb, wTout, x1, x, nullptr, BT, D_MODEL, D_MODEL, D_MODEL, D_MODEL, D_MODEL, 8, 4);

  // ---- phase B: MLP ----
  transpose_cast_kernel<<<dim3(D_FF / 64, D_MODEL / 64), tb, 0, stream>>>(w_g, wTg, D_MODEL, D_FF);
  transpose_cast_kernel<<<dim3(D_FF / 64, D_MODEL / 64), tb, 0, stream>>>(w_u, wTu, D_MODEL, D_FF);
  transpose_cast_kernel<<<dim3(D_MODEL / 64, D_FF / 64), tb, 0, stream>>>(w_o, wTo, D_FF, D_MODEL);
  rmsnorm_cast_kernel<<<BT, 256, 0, stream>>>(x1, g2, hb);

  const int NH = D_FF / 2;  // 4096 ff-columns per half
  for (int half = 0; half < 2; ++half) {
    const unsigned short* wTu_h = wTu + (size_t)half * NH * D_MODEL;
    const unsigned short* wTg_h = wTg + (size_t)half * NH * D_MODEL;
    unsigned short* gb = half ? gbuf1 : gbuf0;
    // up half -> gb (raw u)
    gemm_ks_kernel<0, 2, 4, 8, 4><<<256, 512, 0, stream>>>(
        hb, wTu_h, gb, nullptr, nullptr, BT, NH, D_MODEL, D_MODEL, D_MODEL, NH, 4, 8);
    // gate half, in-place SwiGLU: gb <- silu(h@wTg) * gb
    gemm_ks_kernel<2, 2, 4, 8, 4><<<256, 512, 0, stream>>>(
        hb, wTg_h, gb, gb, nullptr, BT, NH, D_MODEL, D_MODEL, D_MODEL, NH, 4, 8);
  }
  // down: single K=8192 dispatch, A = gbuf0 (k<4096) / gbuf1 (k>=4096)
  gemm_ks_kernel<1, 4, 2, 4, 4, true><<<256, 512, 0, stream>>>(
      gbuf0, wTo, out, x1, gbuf1, BT, D_MODEL, D_FF, NH, D_FF, D_MODEL, 8, 4);
}

// Round 16
// 772.589 us; speedup vs baseline: 1.0093x; 1.0089x over previous
//
#include <hip/hip_runtime.h>

typedef __bf16 bf16x8 __attribute__((ext_vector_type(8)));
typedef float f32x4 __attribute__((ext_vector_type(4)));
typedef unsigned short u16x8 __attribute__((ext_vector_type(8)));

#define B_SZ 2
#define T_SEQ 2048
#define D_MODEL 2048
#define N_HEADS 16
#define D_HEAD 128
#define D_FF 8192
#define BT (B_SZ * T_SEQ)
#define NT (T_SEQ / 64)

__device__ __forceinline__ unsigned short f2bf(float f) {
  unsigned int u = __builtin_bit_cast(unsigned int, f);
  u += 0x7FFFu + ((u >> 16) & 1u);
  return (unsigned short)(u >> 16);
}
__device__ __forceinline__ float bf2f(unsigned short h) {
  unsigned int u = ((unsigned int)h) << 16;
  return __builtin_bit_cast(float, u);
}

__device__ __forceinline__ void load_lds16(const void* g, void* l) {
  __builtin_amdgcn_global_load_lds(
      (const __attribute__((address_space(1))) unsigned int*)g,
      (__attribute__((address_space(3))) unsigned int*)l, 16, 0, 0);
}

template <int N>
__device__ __forceinline__ void vm_gate() {
  if constexpr (N <= 0)
    asm volatile("s_waitcnt vmcnt(0)" ::: "memory");
  else if constexpr (N == 2)
    asm volatile("s_waitcnt vmcnt(2)" ::: "memory");
  else if constexpr (N == 3)
    asm volatile("s_waitcnt vmcnt(3)" ::: "memory");
  else if constexpr (N == 4)
    asm volatile("s_waitcnt vmcnt(4)" ::: "memory");
  else if constexpr (N == 6)
    asm volatile("s_waitcnt vmcnt(6)" ::: "memory");
  else
    asm volatile("s_waitcnt vmcnt(8)" ::: "memory");
}

// ---------------- transpose + cast: in fp32 [R][C] -> out bf16 [C][R] -------
__global__ __launch_bounds__(256) void transpose_cast_kernel(
    const float* __restrict__ in, unsigned short* __restrict__ out, int R, int C) {
  __shared__ float tile[64][65];
  const int tx = threadIdx.x, ty = threadIdx.y;  // [0,16)
  const int c0 = blockIdx.x * 64, r0 = blockIdx.y * 64;
#pragma unroll
  for (int i = 0; i < 4; ++i) {
    const float4 v = *(const float4*)(in + (long)(r0 + ty + 16 * i) * C + c0 + tx * 4);
    float* tr = &tile[ty + 16 * i][tx * 4];
    tr[0] = v.x; tr[1] = v.y; tr[2] = v.z; tr[3] = v.w;
  }
  __syncthreads();
#pragma unroll
  for (int i = 0; i < 4; ++i) {
    const int cc = ty + 16 * i;
    ushort4 o;
    o.x = f2bf(tile[tx * 4 + 0][cc]);
    o.y = f2bf(tile[tx * 4 + 1][cc]);
    o.z = f2bf(tile[tx * 4 + 2][cc]);
    o.w = f2bf(tile[tx * 4 + 3][cc]);
    *(ushort4*)(out + (long)(c0 + cc) * R + r0 + tx * 4) = o;
  }
}

// ---------------- RMSNorm fp32 row -> bf16 ----------------------------------
__global__ __launch_bounds__(256) void rmsnorm_cast_kernel(
    const float* __restrict__ x, const float* __restrict__ gw,
    unsigned short* __restrict__ out) {
  const int row = blockIdx.x;
  const int tid = threadIdx.x;
  const float* xr = x + (long)row * D_MODEL;
  float4 a = *(const float4*)(xr + tid * 8);
  float4 b = *(const float4*)(xr + tid * 8 + 4);
  float ss = a.x * a.x + a.y * a.y + a.z * a.z + a.w * a.w +
             b.x * b.x + b.y * b.y + b.z * b.z + b.w * b.w;
#pragma unroll
  for (int d = 1; d < 64; d <<= 1) ss += __shfl_xor(ss, d);
  __shared__ float part[4];
  if ((tid & 63) == 0) part[tid >> 6] = ss;
  __syncthreads();
  ss = part[0] + part[1] + part[2] + part[3];
  const float rs = rsqrtf(ss * (1.0f / D_MODEL) + 1e-6f);
  float4 g0 = *(const float4*)(gw + tid * 8);
  float4 g1 = *(const float4*)(gw + tid * 8 + 4);
  ushort4 o0, o1;
  o0.x = f2bf(a.x * rs * g0.x); o0.y = f2bf(a.y * rs * g0.y);
  o0.z = f2bf(a.z * rs * g0.z); o0.w = f2bf(a.w * rs * g0.w);
  o1.x = f2bf(b.x * rs * g1.x); o1.y = f2bf(b.y * rs * g1.y);
  o1.z = f2bf(b.z * rs * g1.z); o1.w = f2bf(b.w * rs * g1.w);
  unsigned short* op = out + (long)row * D_MODEL + tid * 8;
  *(ushort4*)op = o0;
  *(ushort4*)(op + 4) = o1;
}

// ---------------- k-slice-ring pipelined GEMM (champion + bank-conflict fix)
// LDS slot layout [row][4 x 16B-unit]; unit XOR-swizzled with (row>>1)&3:
//   LDS[row][u] holds global[row][u ^ ((row>>1)&3)].
// Quarter-wave bank math: read banks (row&1)*16 + u*4 with u = g^((row>>1)&3)
// -> 16 lanes (c=0..15) cover all 8 (parity,unit) groups x 2 lanes = 32 banks,
// 2-way = free (was 8 banks -> 4x floor). Stage source column and fragment
// read unit are per-thread constants:
//   stage: (tid&3) ^ ((tid>>3)&3)   (j-invariant: RPR=128, (j*64)&3 == 0)
//   read : g ^ ((c>>1)&3)           (fragment base multiple of 16)
template <int EPI, int WM, int WN, int FM, int FN, bool DUALA = false>
__global__ __launch_bounds__(WM * WN * 64, 2) void gemm_ks_kernel(
    const unsigned short* __restrict__ A, const unsigned short* __restrict__ Bt,
    void* __restrict__ Cout, const void* __restrict__ aux,
    const unsigned short* __restrict__ A2,
    int M, int N, int K, int lda, int ldb, int ldc, int cm, int cn) {
  constexpr int THREADS = WM * WN * 64;
  constexpr int BM = WM * FM * 16;
  constexpr int BN = WN * FN * 16;
  constexpr int ASLOT = BM * 32;
  constexpr int BSLOT = BN * 32;
  constexpr int RPR = THREADS / 4;
  constexpr int LPS = BM / RPR + BN / RPR;  // loads per slice per thread
  static_assert(RPR == 128, "swizzle j-invariance requires RPR==128");
  __shared__ unsigned short As[4 * ASLOT];
  __shared__ unsigned short Bs[4 * BSLOT];

  const int tid = threadIdx.x;
  const int lane = tid & 63, g = lane >> 4, c = lane & 15;
  const int w = tid >> 6, wr = w / WN, wc = w % WN;

  const int nbn = N / BN;
  const int bid = (int)blockIdx.x;
  const int xcd = bid & 7, idx = bid >> 3;
  const int chn = nbn / cn;
  const int crow = xcd / chn, ccol = xcd % chn;
  const int mr = idx / cn, nc2 = idx % cn;
  const int m0 = (crow * cm + mr) * BM;
  const int n0 = (ccol * cn + nc2) * BN;

  const int nks = K >> 5;
  const int srow = tid >> 2;
  const int ksw = (((tid & 3) ^ ((tid >> 3) & 3))) * 8;  // swizzled source unit
  const unsigned short* A_ = A + (long)m0 * lda;
  const unsigned short* A2_ = DUALA ? (A2 + (long)m0 * lda) : nullptr;
  const unsigned short* B_ = Bt + (long)n0 * ldb;

  auto stage = [&](int s) {
    const int slot = s & 3;
    const long k32 = (long)s * 32;
    const unsigned short* Ab;
    long akofs;
    if constexpr (DUALA) {
      const int khalf = K >> 1;
      const bool lo = k32 < khalf;
      Ab = lo ? A_ : A2_;
      akofs = (lo ? k32 : k32 - khalf) + ksw;
    } else {
      Ab = A_;
      akofs = k32 + ksw;
    }
    const long bkofs = k32 + ksw;
#pragma unroll
    for (int j = 0; j < BM / RPR; ++j)
      load_lds16(Ab + (long)(j * RPR + srow) * lda + akofs,
                 &As[slot * ASLOT + (j * THREADS + tid) * 8]);
#pragma unroll
    for (int j = 0; j < BN / RPR; ++j)
      load_lds16(B_ + (long)(j * RPR + srow) * ldb + bkofs,
                 &Bs[slot * BSLOT + (j * THREADS + tid) * 8]);
  };

  f32x4 acc[FM][FN] = {};

  stage(0);
  if (nks > 1) stage(1);
  if (nks > 2) stage(2);
  vm_gate<2 * LPS>();
  __builtin_amdgcn_sched_barrier(0);
  __builtin_amdgcn_s_barrier();

  const int ru = (g ^ ((c >> 1) & 3)) * 8;  // swizzled read unit offset

  for (int s = 0; s < nks; ++s) {
    const int slot = s & 3;
    const unsigned short* Ap = &As[slot * ASLOT] + (wr * FM * 16 + c) * 32 + ru;
    const unsigned short* Bp = &Bs[slot * BSLOT] + (wc * FN * 16 + c) * 32 + ru;
    bf16x8 fa[FM], fb[FN];
#pragma unroll
    for (int fm = 0; fm < FM; ++fm) fa[fm] = *(const bf16x8*)(Ap + fm * 512);
#pragma unroll
    for (int fn = 0; fn < FN; ++fn) fb[fn] = *(const bf16x8*)(Bp + fn * 512);
    if (s + 3 < nks) stage(s + 3);
    __builtin_amdgcn_s_setprio(1);
#pragma unroll
    for (int fm = 0; fm < FM; ++fm)
#pragma unroll
      for (int fn = 0; fn < FN; ++fn)
        acc[fm][fn] = __builtin_amdgcn_mfma_f32_16x16x32_bf16(fa[fm], fb[fn], acc[fm][fn], 0, 0, 0);
    __builtin_amdgcn_s_setprio(0);
    if (s + 1 == nks) break;
    if (s <= nks - 4)
      vm_gate<2 * LPS>();
    else if (s == nks - 3)
      vm_gate<LPS>();
    else
      vm_gate<0>();
    __builtin_amdgcn_sched_barrier(0);
    __builtin_amdgcn_s_barrier();
  }

#pragma unroll
  for (int fm = 0; fm < FM; ++fm) {
#pragma unroll
    for (int r = 0; r < 4; ++r) {
      const int row = m0 + wr * FM * 16 + fm * 16 + 4 * g + r;
#pragma unroll
      for (int fn = 0; fn < FN; ++fn) {
        const int col = n0 + wc * FN * 16 + fn * 16 + c;
        const long idx2 = (long)row * ldc + col;
        float v = acc[fm][fn][r];
        if constexpr (EPI == 0) {
          ((unsigned short*)Cout)[idx2] = f2bf(v);
        } else if constexpr (EPI == 1) {
          ((float*)Cout)[idx2] = v + ((const float*)aux)[idx2];
        } else {
          const float u = bf2f(((const unsigned short*)aux)[idx2]);
          const float sg = v / (1.0f + __expf(-v));
          ((unsigned short*)Cout)[idx2] = f2bf(sg * u);
        }
      }
    }
  }
}

// ---------------- RoPE tables -----------------------------------------------
__global__ void rope_tables_kernel(float* __restrict__ cost, float* __restrict__ sint) {
  const int idx = blockIdx.x * 256 + threadIdx.x;  // T*64
  const int t = idx >> 6, i = idx & 63;
  const float invf = powf(10000.0f, -(float)i * (1.0f / 64.0f));
  const float ang = (float)t * invf;
  cost[idx] = cosf(ang);
  sint[idx] = sinf(ang);
}

// ---------------- RoPE apply (vectorized 8-wide) on q,k of qkv(bf16) --------
__global__ __launch_bounds__(256) void rope_apply_kernel(
    unsigned short* __restrict__ qkv, const float* __restrict__ cost,
    const float* __restrict__ sint) {
  const long idx = (long)blockIdx.x * 256 + threadIdx.x;  // BT*16*2*8
  const int u = (int)(idx & 7);
  const int h = (int)((idx >> 3) & 15);
  const int qk = (int)((idx >> 7) & 1);
  const long row = idx >> 8;  // 0..BT-1
  const int t = (int)(row & (T_SEQ - 1));
  unsigned short* p = qkv + row * (3 * D_MODEL) + qk * D_MODEL + h * D_HEAD + u * 8;
  u16x8 lo = *(const u16x8*)p;
  u16x8 hi = *(const u16x8*)(p + 64);
  const float4 c0 = *(const float4*)(cost + t * 64 + u * 8);
  const float4 c1 = *(const float4*)(cost + t * 64 + u * 8 + 4);
  const float4 s0 = *(const float4*)(sint + t * 64 + u * 8);
  const float4 s1 = *(const float4*)(sint + t * 64 + u * 8 + 4);
  const float cv[8] = {c0.x, c0.y, c0.z, c0.w, c1.x, c1.y, c1.z, c1.w};
  const float sv[8] = {s0.x, s0.y, s0.z, s0.w, s1.x, s1.y, s1.z, s1.w};
  u16x8 ro, rh;
#pragma unroll
  for (int j = 0; j < 8; ++j) {
    const float a = bf2f(lo[j]);
    const float b = bf2f(hi[j]);
    ro[j] = f2bf(a * cv[j] - b * sv[j]);
    rh[j] = f2bf(b * cv[j] + a * sv[j]);
  }
  *(u16x8*)p = ro;
  *(u16x8*)(p + 64) = rh;
}

// ---------------- V transpose (vectorized): qkv v -> vt [B,H,128,T] ---------
__global__ __launch_bounds__(256) void vtrans_kernel(
    const unsigned short* __restrict__ qkv, unsigned short* __restrict__ vt) {
  __shared__ unsigned short tile[64][68];
  const int tx = threadIdx.x, ty = threadIdx.y;  // [0,16)
  const int t0 = blockIdx.x * 64, d0 = blockIdx.y * 64;
  const int bh = blockIdx.z;  // b*16+h
  const int b = bh >> 4, h = bh & 15;
#pragma unroll
  for (int i = 0; i < 4; ++i) {
    const ushort4 v = *(const ushort4*)(
        qkv + (long)(b * T_SEQ + t0 + ty + 16 * i) * (3 * D_MODEL) + 2 * D_MODEL +
        h * D_HEAD + d0 + tx * 4);
    unsigned short* tr = &tile[ty + 16 * i][tx * 4];
    tr[0] = v.x; tr[1] = v.y; tr[2] = v.z; tr[3] = v.w;
  }
  __syncthreads();
#pragma unroll
  for (int i = 0; i < 4; ++i) {
    const int dd = ty + 16 * i;
    ushort4 o;
    o.x = tile[tx * 4 + 0][dd];
    o.y = tile[tx * 4 + 1][dd];
    o.z = tile[tx * 4 + 2][dd];
    o.w = tile[tx * 4 + 3][dd];
    *(ushort4*)(vt + ((long)bh * D_HEAD + d0 + dd) * T_SEQ + t0 + tx * 4) = o;
  }
}

// ---------------- Flash attention (causal), swapped-QK^T + defer-max --------
__global__ __launch_bounds__(256) void attn_kernel(
    const unsigned short* __restrict__ qkv, const unsigned short* __restrict__ vt,
    unsigned short* __restrict__ ctx) {
  __shared__ unsigned short Ks[2][64 * 128];
  __shared__ unsigned short Vs[2][128 * 64];
  const int h = blockIdx.y, b = blockIdx.z;
  const int tid = threadIdx.x;
  const int w = tid >> 6, lane = tid & 63, g = lane >> 4, c = lane & 15;
  const float scale = 0.08838834764831845f;  // 128^-0.5
  const int srcA = (2 * (g & 1)) * 16 + c;
  const int srcB = srcA + 16;
  const bool hi = (g >> 1) != 0;
  const int bh = b * N_HEADS + h;

  const int ssk = (tid & 15) ^ ((tid >> 4) & 7);
  const int ssv = (tid & 7) ^ ((tid >> 3) & 7);
  const unsigned short* Kg = qkv + (long)b * T_SEQ * 3 * D_MODEL + D_MODEL + (long)h * D_HEAD;
  const unsigned short* Vg = vt + (long)bh * D_HEAD * T_SEQ;

  auto stage = [&](int kv0, int bufi) {
#pragma unroll
    for (int i = 0; i < 4; ++i) {
      const int rowk = i * 16 + (tid >> 4);
      load_lds16(Kg + (long)(kv0 + rowk) * (3 * D_MODEL) + ssk * 8,
                 &Ks[bufi][(i * 256 + tid) * 8]);
    }
#pragma unroll
    for (int i = 0; i < 4; ++i) {
      const int rowv = i * 32 + (tid >> 3);
      load_lds16(Vg + (long)rowv * T_SEQ + kv0 + ssv * 8,
                 &Vs[bufi][(i * 256 + tid) * 8]);
    }
  };

  const int cs7 = c & 7;

  for (int pass = 0; pass < 2; ++pass) {
    const int qt = pass ? (NT - 1 - blockIdx.x) : blockIdx.x;
    const int q = qt * 64 + w * 16 + c;

    bf16x8 fq[4];
    const long rowQ = (long)(b * T_SEQ + q) * (3 * D_MODEL) + h * D_HEAD;
#pragma unroll
    for (int ks = 0; ks < 4; ++ks)
      fq[ks] = *(const bf16x8*)(qkv + rowQ + ks * 32 + g * 8);

    f32x4 o[8] = {};
    float mrun = -INFINITY, ell = 0.0f;

    stage(0, 0);
    asm volatile("s_waitcnt vmcnt(0)" ::: "memory");
    __syncthreads();
    int buf = 0;

    for (int kt = 0; kt <= qt; ++kt) {
      const int kv0 = kt * 64;
      if (kt < qt) stage(kv0 + 64, buf ^ 1);

      f32x4 s[4] = {};
      __builtin_amdgcn_s_setprio(1);
#pragma unroll
      for (int fm = 0; fm < 4; ++fm) {
        const unsigned short* kr = &Ks[buf][(fm * 16 + c) * 128];
#pragma unroll
        for (int ks = 0; ks < 4; ++ks) {
          bf16x8 ak = *(const bf16x8*)(kr + ((ks * 4 + g) ^ cs7) * 8);
          s[fm] = __builtin_amdgcn_mfma_f32_16x16x32_bf16(ak, fq[ks], s[fm], 0, 0, 0);
        }
      }
      __builtin_amdgcn_s_setprio(0);
      float pmax = -INFINITY;
      const bool diag = (kt == qt);
#pragma unroll
      for (int fm = 0; fm < 4; ++fm)
#pragma unroll
        for (int r = 0; r < 4; ++r) {
          float sv = s[fm][r] * scale;
          if (diag) {
            const int kp = kv0 + fm * 16 + 4 * g + r;
            if (kp > q) sv = -INFINITY;
          }
          s[fm][r] = sv;
          pmax = fmaxf(pmax, sv);
        }
      pmax = fmaxf(pmax, __shfl_xor(pmax, 16));
      pmax = fmaxf(pmax, __shfl_xor(pmax, 32));
      if (!__all(pmax <= mrun + 8.0f)) {
        const float mnew = fmaxf(mrun, pmax);
        const float resc = __expf(mrun - mnew);
        ell *= resc;
#pragma unroll
        for (int fm = 0; fm < 8; ++fm) o[fm] *= resc;
        mrun = mnew;
      }
      float rowsum = 0.0f;
#pragma unroll
      for (int fm = 0; fm < 4; ++fm)
#pragma unroll
        for (int r = 0; r < 4; ++r) {
          const float p = __expf(s[fm][r] - mrun);
          s[fm][r] = p;
          rowsum += p;
        }
      rowsum += __shfl_xor(rowsum, 16);
      rowsum += __shfl_xor(rowsum, 32);
      ell += rowsum;

      bf16x8 pb[2];
#pragma unroll
      for (int k2 = 0; k2 < 2; ++k2) {
        float va[4], vb[4];
#pragma unroll
        for (int r = 0; r < 4; ++r) {
          const float t0 = __shfl(s[k2 * 2][r], srcA);
          const float t1 = __shfl(s[k2 * 2 + 1][r], srcA);
          va[r] = hi ? t1 : t0;
          const float u0 = __shfl(s[k2 * 2][r], srcB);
          const float u1 = __shfl(s[k2 * 2 + 1][r], srcB);
          vb[r] = hi ? u1 : u0;
        }
        bf16x8 pv;
        pv[0] = (__bf16)va[0]; pv[1] = (__bf16)va[1];
        pv[2] = (__bf16)va[2]; pv[3] = (__bf16)va[3];
        pv[4] = (__bf16)vb[0]; pv[5] = (__bf16)vb[1];
        pv[6] = (__bf16)vb[2]; pv[7] = (__bf16)vb[3];
        pb[k2] = pv;
      }
      __builtin_amdgcn_s_setprio(1);
#pragma unroll
      for (int fm = 0; fm < 8; ++fm) {
        const unsigned short* vr = &Vs[buf][(fm * 16 + c) * 64];
#pragma unroll
        for (int k2 = 0; k2 < 2; ++k2) {
          bf16x8 av = *(const bf16x8*)(vr + ((k2 * 4 + g) ^ cs7) * 8);
          o[fm] = __builtin_amdgcn_mfma_f32_16x16x32_bf16(av, pb[k2], o[fm], 0, 0, 0);
        }
      }
      __builtin_amdgcn_s_setprio(0);
      asm volatile("s_waitcnt vmcnt(0)" ::: "memory");
      __syncthreads();
      buf ^= 1;
    }

    const float inv = 1.0f / ell;
    unsigned short* outp = ctx + (long)(b * T_SEQ + q) * D_MODEL + h * D_HEAD;
#pragma unroll
    for (int fm = 0; fm < 8; ++fm) {
      ushort4 pk;
      pk.x = f2bf(o[fm][0] * inv);
      pk.y = f2bf(o[fm][1] * inv);
      pk.z = f2bf(o[fm][2] * inv);
      pk.w = f2bf(o[fm][3] * inv);
      *(ushort4*)(outp + fm * 16 + 4 * g) = pk;
    }
  }
}

// ---------------------------------------------------------------------------
extern "C" void kernel_launch(void* const* d_in, const int* in_sizes, int n_in,
                              void* d_out, int out_size, void* d_ws, size_t ws_size,
                              hipStream_t stream) {
  const float* x = (const float*)d_in[0];
  const float* w_qkv = (const float*)d_in[1];
  const float* w_out = (const float*)d_in[2];
  const float* g1 = (const float*)d_in[3];
  const float* g2 = (const float*)d_in[4];
  const float* w_g = (const float*)d_in[5];
  const float* w_u = (const float*)d_in[6];
  const float* w_o = (const float*)d_in[7];
  float* out = (float*)d_out;

  char* ws = (char*)d_ws;
  size_t off = 0;
  auto take = [&](size_t bytes) {
    char* p = ws + off;
    off += (bytes + 255) & ~(size_t)255;
    return p;
  };

  char* Wreg = take((size_t)3 * D_FF * D_MODEL * 2);  // 100.66 MB
  unsigned short* wTqkv = (unsigned short*)Wreg;
  unsigned short* wTout = (unsigned short*)(Wreg + (size_t)3 * D_MODEL * D_MODEL * 2);
  unsigned short* wTg = (unsigned short*)Wreg;
  unsigned short* wTu = (unsigned short*)(Wreg + (size_t)D_FF * D_MODEL * 2);
  unsigned short* wTo = (unsigned short*)(Wreg + (size_t)2 * D_FF * D_MODEL * 2);

  const size_t qkv_b = (size_t)BT * 3 * D_MODEL * 2;
  const size_t vt_b = (size_t)B_SZ * N_HEADS * D_HEAD * T_SEQ * 2;
  const size_t ctx_b = (size_t)BT * D_MODEL * 2;
  char* AR = take(qkv_b + vt_b + ctx_b);  // 83.9 MB
  unsigned short* qkvb = (unsigned short*)AR;
  unsigned short* vtb = (unsigned short*)(AR + qkv_b);
  unsigned short* ctxb = (unsigned short*)(AR + qkv_b + vt_b);
  unsigned short* gbuf0 = (unsigned short*)AR;                                   // 33.6 MB
  unsigned short* gbuf1 = (unsigned short*)(AR + (size_t)BT * (D_FF / 2) * 2);   // 33.6 MB

  float* x1 = (float*)take((size_t)BT * D_MODEL * 4);
  unsigned short* hb = (unsigned short*)take((size_t)BT * D_MODEL * 2);
  float* cost = (float*)take((size_t)T_SEQ * 64 * 4);
  float* sint = (float*)take((size_t)T_SEQ * 64 * 4);

  const dim3 tb(16, 16);

  // ---- phase A: attention ----
  transpose_cast_kernel<<<dim3(3 * D_MODEL / 64, D_MODEL / 64), tb, 0, stream>>>(w_qkv, wTqkv, D_MODEL, 3 * D_MODEL);
  transpose_cast_kernel<<<dim3(D_MODEL / 64, D_MODEL / 64), tb, 0, stream>>>(w_out, wTout, D_MODEL, D_MODEL);
  rope_tables_kernel<<<T_SEQ * 64 / 256, 256, 0, stream>>>(cost, sint);

  rmsnorm_cast_kernel<<<BT, 256, 0, stream>>>(x, g1, hb);
  // QKV: 256^2; nbm=16, nbn=24 -> 384 blocks, XCD rect 8x6
  gemm_ks_kernel<0, 2, 4, 8, 4><<<384, 512, 0, stream>>>(
      hb, wTqkv, qkvb, nullptr, nullptr, BT, 3 * D_MODEL, D_MODEL, D_MODEL, D_MODEL, 3 * D_MODEL, 8, 6);
  rope_apply_kernel<<<(BT * N_HEADS * 2 * 8) / 256, 256, 0, stream>>>(qkvb, cost, sint);
  vtrans_kernel<<<dim3(T_SEQ / 64, D_HEAD / 64, B_SZ * N_HEADS), tb, 0, stream>>>(qkvb, vtb);
  attn_kernel<<<dim3(NT / 2, N_HEADS, B_SZ), 256, 0, stream>>>(qkvb, vtb, ctxb);
  // out-proj: 256x128; 256 blocks, rect 8x4
  gemm_ks_kernel<1, 4, 2, 4, 4><<<256, 512, 0, stream>>>(
      ctxb, wTout, x1, x, nullptr, BT, D_MODEL, D_MODEL, D_MODEL, D_MODEL, D_MODEL, 8, 4);

  // ---- phase B: MLP ----
  transpose_cast_kernel<<<dim3(D_FF / 64, D_MODEL / 64), tb, 0, stream>>>(w_g, wTg, D_MODEL, D_FF);
  transpose_cast_kernel<<<dim3(D_FF / 64, D_MODEL / 64), tb, 0, stream>>>(w_u, wTu, D_MODEL, D_FF);
  transpose_cast_kernel<<<dim3(D_MODEL / 64, D_FF / 64), tb, 0, stream>>>(w_o, wTo, D_FF, D_MODEL);
  rmsnorm_cast_kernel<<<BT, 256, 0, stream>>>(x1, g2, hb);

  const int NH = D_FF / 2;  // 4096 ff-columns per half
  for (int half = 0; half < 2; ++half) {
    const unsigned short* wTu_h = wTu + (size_t)half * NH * D_MODEL;
    const unsigned short* wTg_h = wTg + (size_t)half * NH * D_MODEL;
    unsigned short* gb = half ? gbuf1 : gbuf0;
    // up half -> gb (raw u)
    gemm_ks_kernel<0, 2, 4, 8, 4><<<256, 512, 0, stream>>>(
        hb, wTu_h, gb, nullptr, nullptr, BT, NH, D_MODEL, D_MODEL, D_MODEL, NH, 4, 8);
    // gate half, in-place SwiGLU: gb <- silu(h@wTg) * gb
    gemm_ks_kernel<2, 2, 4, 8, 4><<<256, 512, 0, stream>>>(
        hb, wTg_h, gb, gb, nullptr, BT, NH, D_MODEL, D_MODEL, D_MODEL, NH, 4, 8);
  }
  // down: single K=8192 dispatch, A = gbuf0 (k<4096) / gbuf1 (k>=4096)
  gemm_ks_kernel<1, 4, 2, 4, 4, true><<<256, 512, 0, stream>>>(
      gbuf0, wTo, out, x1, gbuf1, BT, D_MODEL, D_FF, NH, D_FF, D_MODEL, 8, 4);
}